// Round 11
// baseline (217.692 us; speedup 1.0000x reference)
//
#include <hip/hip_runtime.h>

#define B_ 8
#define S_ 4096
#define D_ 1024
#define N_ 128
#define K_ 8
#define NEG_INF_ (-1e9f)

// ---- Kernel 1: per-token dot (round-7 strided pattern, unchanged) + fused
// ---- selection: the block that completes each batch's cohort runs select.
// Cohort structure: blocks 0..1023 cover tokens [0,4096)+strides -> batches
// {0,2,4,6}; blocks 1024..2047 -> batches {1,3,5,7}. Each batch's tok_dots are
// produced by exactly the 1024 blocks of its cohort. Every block increments 4
// batch counters AFTER __threadfence (release); the block receiving ticket
// 1023 for counter[b] knows all stores for batch b are device-visible
// (acquire via threadfence after the atomic) and runs select for b inline.
// No spin loops -> no co-residency assumptions, deadlock-free.
__global__ __launch_bounds__(256, 8)
void tok_dot_select_kernel(const float* __restrict__ h,
                           const float* __restrict__ cls_w,
                           const int* __restrict__ ind,        // [B,S]
                           const float* __restrict__ cls_b,    // [1]
                           float* __restrict__ tok_dot,        // [B*S]
                           int* __restrict__ counters,         // [8]
                           float* __restrict__ out_selected,   // [B,N]
                           float* __restrict__ out_logits,     // [K,B,N]
                           float* __restrict__ out_mask) {     // [B,S]
    const int tid = threadIdx.x;
    const int lane = tid & 63;
    const int gw = (blockIdx.x << 2) + (tid >> 6);  // 0..8191
    const int dofs = lane * 4;

    // ---------------- tok_dot phase (identical to round 7) ----------------
    {
        const float4 w0 = *reinterpret_cast<const float4*>(cls_w + 0 * 256 + dofs);
        const float4 w1 = *reinterpret_cast<const float4*>(cls_w + 1 * 256 + dofs);
        const float4 w2 = *reinterpret_cast<const float4*>(cls_w + 2 * 256 + dofs);
        const float4 w3 = *reinterpret_cast<const float4*>(cls_w + 3 * 256 + dofs);

        float acc[4];
        #pragma unroll
        for (int t = 0; t < 4; ++t) {
            const float* p = h + (size_t)(gw + t * 8192) * D_;
            const float4 v0 = *reinterpret_cast<const float4*>(p + 0 * 256 + dofs);
            const float4 v1 = *reinterpret_cast<const float4*>(p + 1 * 256 + dofs);
            const float4 v2 = *reinterpret_cast<const float4*>(p + 2 * 256 + dofs);
            const float4 v3 = *reinterpret_cast<const float4*>(p + 3 * 256 + dofs);
            acc[t] = v0.x * w0.x + v0.y * w0.y + v0.z * w0.z + v0.w * w0.w
                   + v1.x * w1.x + v1.y * w1.y + v1.z * w1.z + v1.w * w1.w
                   + v2.x * w2.x + v2.y * w2.y + v2.z * w2.z + v2.w * w2.w
                   + v3.x * w3.x + v3.y * w3.y + v3.z * w3.z + v3.w * w3.w;
        }
        for (int off = 32; off > 0; off >>= 1) {
            #pragma unroll
            for (int t = 0; t < 4; ++t) acc[t] += __shfl_down(acc[t], off, 64);
        }
        if (lane == 0) {
            #pragma unroll
            for (int t = 0; t < 4; ++t) tok_dot[gw + t * 8192] = acc[t];
        }
    }

    // ---------------- completion accounting ----------------
    __shared__ int do_batch[4];
    __shared__ float sh_part[256];
    __shared__ int   sh_s0[N_], sh_s1[N_];
    __shared__ float sh_dseg[N_], sh_len[N_], sh_msk[N_], sh_sel[N_];

    __syncthreads();   // drains this block's tok_dot stores (vmcnt0 before barrier)
    if (tid == 0) {
        __threadfence();                        // release: our stores device-visible
        const int c = (blockIdx.x >= 1024) ? 1 : 0;
        #pragma unroll
        for (int j = 0; j < 4; ++j) {
            const int b = c + 2 * j;
            const int t = atomicAdd(&counters[b], 1);
            do_batch[j] = (t == 1023) ? b : -1;
        }
    }
    __syncthreads();

    // ---------------- select phase (runs in at most a few blocks) ----------
    for (int j = 0; j < 4; ++j) {
        const int b = do_batch[j];              // block-uniform
        if (b < 0) continue;
        __threadfence();                        // acquire: other blocks' stores visible

        const int*   sib = ind + b * S_;        // L2-hot (16 KB)
        const float* tdb = tok_dot + b * S_;    // L2-hot (16 KB)

        {
            const int n = tid & (N_ - 1);
            int lo = 0, hi = S_;
            while (lo < hi) { int mid = (lo + hi) >> 1; if (sib[mid] < n) lo = mid + 1; else hi = mid; }
            const int s0 = lo;
            lo = s0; hi = S_;
            while (lo < hi) { int mid = (lo + hi) >> 1; if (sib[mid] < n + 1) lo = mid + 1; else hi = mid; }
            const int s1 = lo;
            const int mid = (s0 + s1) >> 1;
            const int a = (tid < N_) ? s0 : mid;
            const int e = (tid < N_) ? mid : s1;
            float acc = 0.f;
            for (int s = a; s < e; ++s) acc += tdb[s];   // sorted order = ref assoc
            sh_part[tid] = acc;
            if (tid < N_) { sh_s0[tid] = s0; sh_s1[tid] = s1; }
        }
        __syncthreads();
        if (tid < N_) {
            const int s0 = sh_s0[tid], s1 = sh_s1[tid];
            sh_dseg[tid] = sh_part[tid] + sh_part[tid + N_];
            sh_len[tid]  = fmaxf((float)(s1 - s0), 1.0f);
            sh_msk[tid]  = (s1 > s0) ? 1.f : 0.f;
        }
        __syncthreads();

        if (tid < 64) {
            const float bias = cls_b[0];
            const float d0 = sh_dseg[tid],      d1 = sh_dseg[tid + 64];
            const float l0 = sh_len[tid],       l1 = sh_len[tid + 64];
            float m0 = sh_msk[tid],             m1 = sh_msk[tid + 64];
            float sel0 = 0.f, sel1 = 0.f;
            float dot = 0.f, len = 0.f;

            for (int k = 0; k < K_; ++k) {
                const float lg0 = (m0 > 0.f) ? (dot + d0) / (len + l0) + bias : NEG_INF_;
                const float lg1 = (m1 > 0.f) ? (dot + d1) / (len + l1) + bias : NEG_INF_;
                out_logits[(size_t)k * (B_ * N_) + b * N_ + tid]      = lg0;
                out_logits[(size_t)k * (B_ * N_) + b * N_ + tid + 64] = lg1;
                float bv; int bi;
                if (lg0 >= lg1) { bv = lg0; bi = tid; } else { bv = lg1; bi = tid + 64; }
                for (int off = 32; off > 0; off >>= 1) {
                    const float ov = __shfl_xor(bv, off, 64);
                    const int   oi = __shfl_xor(bi, off, 64);
                    if (ov > bv || (ov == bv && oi < bi)) { bv = ov; bi = oi; }
                }
                const float dsrc = (bi < 64) ? d0 : d1;   // uniform condition
                const float lsrc = (bi < 64) ? l0 : l1;
                dot += __shfl(dsrc, bi & 63, 64);
                len += __shfl(lsrc, bi & 63, 64);
                if ((bi & 63) == tid) {
                    if (bi < 64) { m0 = 0.f; sel0 = 1.f; }
                    else         { m1 = 0.f; sel1 = 1.f; }
                }
            }
            out_selected[b * N_ + tid]      = sel0;
            out_selected[b * N_ + tid + 64] = sel1;
            sh_sel[tid]      = sel0;
            sh_sel[tid + 64] = sel1;
        }
        __syncthreads();
        for (int s = tid; s < S_; s += 256) {
            out_mask[b * S_ + s] = sh_sel[sib[s]];
        }
        __syncthreads();   // protect shared arrays for a possible next j
    }
}

// ---------------- Kernel 2: write phase (round-7, unchanged) -----------------
#define TPB_ 16
__global__ void write_kernel(const float* __restrict__ h,
                             const float* __restrict__ out_mask,  // [B,S]
                             float* __restrict__ out_masked) {    // [B,S,D]
    const int t0 = blockIdx.x * TPB_;
    const int tid = threadIdx.x;
    float m[TPB_];
    #pragma unroll
    for (int i = 0; i < TPB_; ++i) m[i] = out_mask[t0 + i];
    const float4 z = make_float4(0.f, 0.f, 0.f, 0.f);
    #pragma unroll
    for (int i = 0; i < TPB_; ++i) {
        if (m[i] == 0.f) {
            const size_t base = (size_t)(t0 + i) * D_ + tid * 4;
            *reinterpret_cast<float4*>(out_masked + base) = z;
        }
    }
    #pragma unroll
    for (int i = 0; i < TPB_; ++i) {
        if (m[i] != 0.f) {
            const size_t base = (size_t)(t0 + i) * D_ + tid * 4;
            *reinterpret_cast<float4*>(out_masked + base) =
                *reinterpret_cast<const float4*>(h + base);
        }
    }
}

extern "C" void kernel_launch(void* const* d_in, const int* in_sizes, int n_in,
                              void* d_out, int out_size, void* d_ws, size_t ws_size,
                              hipStream_t stream) {
    const float* h     = (const float*)d_in[0];
    const int*   ind   = (const int*)d_in[1];
    const float* cls_w = (const float*)d_in[2];
    const float* cls_b = (const float*)d_in[3];

    float* out = (float*)d_out;
    float* out_selected = out;                         // [B,N]    1024
    float* out_logits   = out + 1024;                  // [K,B,N]  8192
    float* out_mask     = out + 1024 + 8192;           // [B,S]    32768
    float* out_masked   = out + 1024 + 8192 + 32768;   // [B,S,D]

    char* ws = (char*)d_ws;
    float* tok_dot  = (float*)ws;                         // B*S floats = 128 KB
    int*   counters = (int*)(ws + (size_t)B_ * S_ * 4);   // 8 ints

    hipMemsetAsync(counters, 0, 8 * sizeof(int), stream);
    tok_dot_select_kernel<<<dim3(2048), dim3(256), 0, stream>>>(
        h, cls_w, ind, cls_b, tok_dot, counters,
        out_selected, out_logits, out_mask);
    write_kernel<<<dim3(B_ * S_ / TPB_), dim3(256), 0, stream>>>(h, out_mask, out_masked);
}

// Round 12
// 56.629 us; speedup vs baseline: 3.8442x; 3.8442x over previous
//
#include <hip/hip_runtime.h>

#define B_ 8
#define S_ 4096
#define D_ 1024
#define N_ 128
#define K_ 8
#define NEG_INF_ (-1e9f)

// ---------------- Kernel 1: per-token dot with cls_w (pure-read phase) -------
// One wave per 4 tokens (strided 8192 apart: whole device sweeps one
// contiguous 33 MB window at a time), 16 float4 loads in flight, then 4
// interleaved shuffle-reduce chains. 8192 waves = 32 waves/CU.
__global__ void tok_dot_kernel(const float* __restrict__ h,
                               const float* __restrict__ cls_w,
                               float* __restrict__ tok_dot) {   // [B*S]
    const int lane = threadIdx.x & 63;
    const int gw = (blockIdx.x << 2) + (threadIdx.x >> 6);  // 0..8191
    const int dofs = lane * 4;

    const float4 w0 = *reinterpret_cast<const float4*>(cls_w + 0 * 256 + dofs);
    const float4 w1 = *reinterpret_cast<const float4*>(cls_w + 1 * 256 + dofs);
    const float4 w2 = *reinterpret_cast<const float4*>(cls_w + 2 * 256 + dofs);
    const float4 w3 = *reinterpret_cast<const float4*>(cls_w + 3 * 256 + dofs);

    float acc[4];
    #pragma unroll
    for (int t = 0; t < 4; ++t) {
        const float* p = h + (size_t)(gw + t * 8192) * D_;
        const float4 v0 = *reinterpret_cast<const float4*>(p + 0 * 256 + dofs);
        const float4 v1 = *reinterpret_cast<const float4*>(p + 1 * 256 + dofs);
        const float4 v2 = *reinterpret_cast<const float4*>(p + 2 * 256 + dofs);
        const float4 v3 = *reinterpret_cast<const float4*>(p + 3 * 256 + dofs);
        acc[t] = v0.x * w0.x + v0.y * w0.y + v0.z * w0.z + v0.w * w0.w
               + v1.x * w1.x + v1.y * w1.y + v1.z * w1.z + v1.w * w1.w
               + v2.x * w2.x + v2.y * w2.y + v2.z * w2.z + v2.w * w2.w
               + v3.x * w3.x + v3.y * w3.y + v3.z * w3.z + v3.w * w3.w;
    }
    for (int off = 32; off > 0; off >>= 1) {
        #pragma unroll
        for (int t = 0; t < 4; ++t) acc[t] += __shfl_down(acc[t], off, 64);
    }
    if (lane == 0) {
        #pragma unroll
        for (int t = 0; t < 4; ++t) tok_dot[gw + t * 8192] = acc[t];
    }
}

// ---------------- Kernel 2: segment-sum + greedy selection + mask ------------
// One block per batch. Segment sums use 2 threads/sentence; K-loop runs in
// wave 0 with register state and butterfly shfl_xor argmax -- no syncs inside.
__global__ void select_kernel(const float* __restrict__ tok_dot,  // [B,S]
                              const int* __restrict__ ind,        // [B,S]
                              const float* __restrict__ cls_b,    // [1]
                              float* __restrict__ out_selected,   // [B,N]
                              float* __restrict__ out_logits,     // [K,B,N]
                              float* __restrict__ out_mask) {     // [B,S]
    const int b = blockIdx.x;
    const int tid = threadIdx.x;  // 256 threads

    __shared__ float td[S_];
    __shared__ int   si[S_];
    __shared__ float sh_part[256];
    __shared__ int   sh_s0[N_], sh_s1[N_];
    __shared__ float sh_dseg[N_], sh_len[N_], sh_msk[N_], sh_sel[N_];

    for (int s = tid; s < S_; s += 256) {
        td[s] = tok_dot[b * S_ + s];
        si[s] = ind[b * S_ + s];
    }
    __syncthreads();

    {
        const int n = tid & (N_ - 1);
        int lo = 0, hi = S_;
        while (lo < hi) { int mid = (lo + hi) >> 1; if (si[mid] < n) lo = mid + 1; else hi = mid; }
        const int s0 = lo;
        lo = s0; hi = S_;
        while (lo < hi) { int mid = (lo + hi) >> 1; if (si[mid] < n + 1) lo = mid + 1; else hi = mid; }
        const int s1 = lo;
        const int mid = (s0 + s1) >> 1;
        const int a = (tid < N_) ? s0 : mid;
        const int e = (tid < N_) ? mid : s1;
        float acc = 0.f;
        for (int s = a; s < e; ++s) acc += td[s];
        sh_part[tid] = acc;
        if (tid < N_) { sh_s0[tid] = s0; sh_s1[tid] = s1; }
    }
    __syncthreads();
    if (tid < N_) {
        const int s0 = sh_s0[tid], s1 = sh_s1[tid];
        sh_dseg[tid] = sh_part[tid] + sh_part[tid + N_];
        sh_len[tid]  = fmaxf((float)(s1 - s0), 1.0f);
        sh_msk[tid]  = (s1 > s0) ? 1.f : 0.f;
    }
    __syncthreads();

    if (tid < 64) {
        const float bias = cls_b[0];
        const float d0 = sh_dseg[tid],      d1 = sh_dseg[tid + 64];
        const float l0 = sh_len[tid],       l1 = sh_len[tid + 64];
        float m0 = sh_msk[tid],             m1 = sh_msk[tid + 64];
        float sel0 = 0.f, sel1 = 0.f;
        float dot = 0.f, len = 0.f;

        for (int k = 0; k < K_; ++k) {
            const float lg0 = (m0 > 0.f) ? (dot + d0) / (len + l0) + bias : NEG_INF_;
            const float lg1 = (m1 > 0.f) ? (dot + d1) / (len + l1) + bias : NEG_INF_;
            out_logits[(size_t)k * (B_ * N_) + b * N_ + tid]      = lg0;
            out_logits[(size_t)k * (B_ * N_) + b * N_ + tid + 64] = lg1;
            float bv; int bi;
            if (lg0 >= lg1) { bv = lg0; bi = tid; } else { bv = lg1; bi = tid + 64; }
            for (int off = 32; off > 0; off >>= 1) {
                const float ov = __shfl_xor(bv, off, 64);
                const int   oi = __shfl_xor(bi, off, 64);
                if (ov > bv || (ov == bv && oi < bi)) { bv = ov; bi = oi; }
            }
            const float dsrc = (bi < 64) ? d0 : d1;   // uniform condition
            const float lsrc = (bi < 64) ? l0 : l1;
            dot += __shfl(dsrc, bi & 63, 64);
            len += __shfl(lsrc, bi & 63, 64);
            if ((bi & 63) == tid) {
                if (bi < 64) { m0 = 0.f; sel0 = 1.f; }
                else         { m1 = 0.f; sel1 = 1.f; }
            }
        }
        out_selected[b * N_ + tid]      = sel0;
        out_selected[b * N_ + tid + 64] = sel1;
        sh_sel[tid]      = sel0;
        sh_sel[tid + 64] = sel1;
    }
    __syncthreads();
    for (int s = tid; s < S_; s += 256) {
        out_mask[b * S_ + s] = sh_sel[si[s]];
    }
}

// ---------------- Kernel 3: write phase (pure streaming stores) --------------
// 16 tokens per block -> 2048 blocks = 32 resident waves/CU. Zeros-loop first
// (unbroken store stream, ~94% of tokens), then copy-loop for selected tokens
// (h is L3-resident after kernel 1).
#define TPB_ 16
__global__ void write_kernel(const float* __restrict__ h,
                             const float* __restrict__ out_mask,  // [B,S]
                             float* __restrict__ out_masked) {    // [B,S,D]
    const int t0 = blockIdx.x * TPB_;
    const int tid = threadIdx.x;
    float m[TPB_];
    #pragma unroll
    for (int i = 0; i < TPB_; ++i) m[i] = out_mask[t0 + i];
    const float4 z = make_float4(0.f, 0.f, 0.f, 0.f);
    #pragma unroll
    for (int i = 0; i < TPB_; ++i) {
        if (m[i] == 0.f) {
            const size_t base = (size_t)(t0 + i) * D_ + tid * 4;
            *reinterpret_cast<float4*>(out_masked + base) = z;
        }
    }
    #pragma unroll
    for (int i = 0; i < TPB_; ++i) {
        if (m[i] != 0.f) {
            const size_t base = (size_t)(t0 + i) * D_ + tid * 4;
            *reinterpret_cast<float4*>(out_masked + base) =
                *reinterpret_cast<const float4*>(h + base);
        }
    }
}

extern "C" void kernel_launch(void* const* d_in, const int* in_sizes, int n_in,
                              void* d_out, int out_size, void* d_ws, size_t ws_size,
                              hipStream_t stream) {
    const float* h     = (const float*)d_in[0];
    const int*   ind   = (const int*)d_in[1];
    const float* cls_w = (const float*)d_in[2];
    const float* cls_b = (const float*)d_in[3];

    float* out = (float*)d_out;
    float* out_selected = out;                         // [B,N]    1024
    float* out_logits   = out + 1024;                  // [K,B,N]  8192
    float* out_mask     = out + 1024 + 8192;           // [B,S]    32768
    float* out_masked   = out + 1024 + 8192 + 32768;   // [B,S,D]

    float* tok_dot = (float*)d_ws;                     // B*S floats = 128 KB

    tok_dot_kernel<<<dim3(2048), dim3(256), 0, stream>>>(h, cls_w, tok_dot);
    select_kernel<<<dim3(B_), dim3(256), 0, stream>>>(tok_dot, ind, cls_b,
                                                      out_selected, out_logits,
                                                      out_mask);
    write_kernel<<<dim3(B_ * S_ / TPB_), dim3(256), 0, stream>>>(h, out_mask, out_masked);
}